// Round 11
// baseline (434.881 us; speedup 1.0000x reference)
//
#include <hip/hip_runtime.h>
#include <hip/hip_cooperative_groups.h>
#include <hip/hip_bf16.h>

namespace cg = cooperative_groups;

#define N_NODES 16000
#define N_EDGES 80000
#define N_GRAPHS 64

#define SILU_NORM 1.679177f
#define SMOOTH_C (1.14136f * 7.38905609893065f)   // 1.14136*e^2
#define SQRT10 3.16227766016838f
#define INV_SQRT10 0.316227766016838f
#define SQRT3 1.7320508075688772f
#define QK_NORM 0.04419417382415922f              // 1/sqrt(2*16*16)
#define SCALE_B 0.02209708691207961f              // (1/8)*(1/sqrt(32))
#define RSTEP (11.0f / 6.0f)
#define BC (SMOOTH_C * SQRT10)

#define NTHR 256
#define NCHUNK 313       // ceil(80000/256) edge chunks
#define NB_V 1460        // virtual edge buckets (64 slots each)
#define NACC_MAX 256

struct Params {
    const float *pos, *z_table, *mol_table, *Wq, *W1k, *W2k, *W1v, *W2v, *Wa;
    const int *xarr, *molid, *esrc, *edst, *batch;
    float4 *nodeinfo; float *zbuf;
    int *hist; int *meta; int *sbase_g; int *csbuf;
    int2 *spair;
    float *BkT, *Bv0T, *Bv1T, *qa;
    float4 *geomexp; int *pkbuf; float2 *vsbuf;
    float *partial; float *out;
};

union Sh {
    struct { float Bk[576], Bv0[576], Bv1[576], w1k[330], w1v[330], hk[576], hv[576]; } e;
    struct { float a[N_GRAPHS * 68]; } acc;            // 17408 B (largest)
    struct { int h[200]; } hist;
    struct { int cnt[200]; int off[201]; } scan;
    struct { int sbase[200]; int cnt2[200]; } scat;
    struct { float wqa[1024]; } qa;
    struct { float w2s[1024]; } tb;
};

__device__ __forceinline__ float sus_f(float x) {
    return x > 0.0f ? __expf(-__fdividef(1.0f, x)) : 0.0f;
}
__device__ __forceinline__ float bval(float d) {
    float pd = 1.0f + d, md = 1.0f - d;
    float e = __expf(-(__fdividef(1.0f, pd) + __fdividef(1.0f, md)));
    return (pd > 0.0f && md > 0.0f) ? BC * e : 0.0f;
}
__device__ __forceinline__ float silu_n(float s) {
    return __fdividef(SILU_NORM * s, 1.0f + __expf(-s));
}

__global__ void __launch_bounds__(NTHR) fused(Params p) {
    __shared__ Sh sh;
    cg::grid_group grid = cg::this_grid();
    int b = blockIdx.x, tid = threadIdx.x;
    int G = gridDim.x;
    int lane = tid & 15, grp = tid >> 4;

    // ---------- phase 1: hist chunks | nodeinfo | B-tables | qa ----------
    for (int ch = b; ch < NCHUNK; ch += G) {
        if (tid < 200) sh.hist.h[tid] = 0;
        __syncthreads();
        int e = ch * NTHR + tid;
        if (e < N_EDGES) {
            int s = p.esrc[e];
            int cs = p.xarr[s] * 2 + p.molid[s];
            p.csbuf[e] = cs;
            atomicAdd(&sh.hist.h[cs], 1);
        }
        __syncthreads();
        if (tid < 200) p.hist[ch * 200 + tid] = sh.hist.h[tid];
        __syncthreads();
    }
    for (int i = b * NTHR + tid; i < N_NODES; i += G * NTHR) {
        int combo = p.xarr[i] * 2 + p.molid[i];
        p.nodeinfo[i] = make_float4(p.pos[3 * i], p.pos[3 * i + 1], p.pos[3 * i + 2],
                                    __int_as_float(combo | (p.batch[i] << 8)));
        p.zbuf[i] = 0.0f;
    }
    for (int r = b; r < 97; r += G) {
        __syncthreads();
        if (r == 96) {
            for (int o = tid; o < 1024; o += NTHR) {
                int u = o >> 4, w = o & 15;
                float s = 0.0f;
                for (int v = 0; v < 16; ++v) s += p.Wq[u * 16 + v] * p.Wa[v * 16 + w];
                sh.qa.wqa[o] = s;
            }
            __syncthreads();
            for (int o = tid; o < 3200; o += NTHR) {
                int combo = o >> 4, w = o & 15;
                int elem = combo >> 1, mol = combo & 1;
                float s = 0.0f;
                for (int u = 0; u < 48; ++u) s += p.z_table[elem * 48 + u] * sh.qa.wqa[u * 16 + w];
                for (int u = 0; u < 16; ++u) s += p.mol_table[mol * 16 + u] * sh.qa.wqa[(48 + u) * 16 + w];
                p.qa[combo * 16 + w] = s * 0.125f * QK_NORM;
            }
        } else {
            int t = r >> 5, m = r & 31;          // t: 0=k,1=v0,2=v1
            const float* srcp = (t == 0) ? (p.W2k + m * 2048)
                              : (t == 1) ? (p.W2v + m * 2048)
                                         : (p.W2v + m * 2048 + 1024);
            for (int i = tid; i < 1024; i += NTHR) sh.tb.w2s[i] = srcp[i];  // [u][w]
            __syncthreads();
            float* dstT = (t == 0) ? p.BkT : (t == 1) ? p.Bv0T : p.Bv1T;
            for (int o = tid; o < 3200; o += NTHR) {
                int combo = o >> 4, w = o & 15;
                int elem = combo >> 1, mol = combo & 1;
                float s = 0.0f;
                for (int u = 0; u < 48; ++u) s += p.z_table[elem * 48 + u] * sh.tb.w2s[u * 16 + w];
                for (int u = 0; u < 16; ++u) s += p.mol_table[mol * 16 + u] * sh.tb.w2s[(48 + u) * 16 + w];
                dstT[combo * 512 + w * 32 + m] = s * SCALE_B;
            }
        }
    }
    grid.sync();

    // ---------- phase 2: scan (block 0) ----------
    if (b == 0) {
        __syncthreads();
        if (tid < 200) {
            int t = 0;
            for (int c = 0; c < NCHUNK; ++c) t += p.hist[c * 200 + tid];
            sh.scan.cnt[tid] = t;
        }
        __syncthreads();
        if (tid == 0) {
            int acc = 0;
            for (int c = 0; c < 200; ++c) { sh.scan.off[c] = acc; acc += (sh.scan.cnt[c] + 63) & ~63; }
            sh.scan.off[200] = acc;
        }
        __syncthreads();
        if (tid < 200) p.meta[tid] = sh.scan.cnt[tid];
        if (tid < 201) p.meta[400 + tid] = sh.scan.off[tid];
        if (tid == 0) p.meta[601] = sh.scan.off[200];
        if (tid < 200) {
            int run = sh.scan.off[tid];
            for (int c = 0; c < NCHUNK; ++c) { p.sbase_g[c * 200 + tid] = run; run += p.hist[c * 200 + tid]; }
        }
    }
    grid.sync();

    // ---------- phase 3: scatter ----------
    for (int ch = b; ch < NCHUNK; ch += G) {
        __syncthreads();
        if (tid < 200) { sh.scat.sbase[tid] = p.sbase_g[ch * 200 + tid]; sh.scat.cnt2[tid] = 0; }
        __syncthreads();
        int e = ch * NTHR + tid;
        if (e < N_EDGES) {
            int cs = p.csbuf[e];
            int r = atomicAdd(&sh.scat.cnt2[cs], 1);
            p.spair[sh.scat.sbase[cs] + r] = make_int2(p.esrc[e], p.edst[e]);
        }
    }
    grid.sync();

    // ---------- phase 4: bucketed edge compute ----------
    int ptot = p.meta[601];
    const int* poff = p.meta + 400;
    for (int vb = b; vb < NB_V; vb += G) {
        int base_s = vb * 64;
        if (base_s < ptot) {
            __syncthreads();                      // LDS reuse guard
            int lo = 0, hi = 200;
            while (lo < hi) { int m = (lo + hi) >> 1; if (poff[m + 1] <= base_s) lo = m + 1; else hi = m; }
            int combo = lo;
            int vend = poff[combo] + p.meta[combo];
            for (int o = tid; o < 512; o += NTHR) {
                int w = o >> 5, m = o & 31;
                sh.e.Bk [w * 36 + m] = p.BkT [combo * 512 + o];
                sh.e.Bv0[w * 36 + m] = p.Bv0T[combo * 512 + o];
                sh.e.Bv1[w * 36 + m] = p.Bv1T[combo * 512 + o];
            }
            for (int o = tid; o < 330; o += NTHR) {
                int i = o / 33, ch2 = o % 33;
                if (ch2 < 32) { sh.e.w1k[o] = p.W1k[i * 32 + ch2]; sh.e.w1v[o] = p.W1v[i * 32 + ch2]; }
            }
            __syncthreads();
#pragma unroll
            for (int it = 0; it < 4; ++it) {
                int idx = base_s + it * 16 + grp;
                if (idx < vend) {
                    int2 sd = p.spair[idx];
                    float4 ns = p.nodeinfo[sd.x];
                    float4 nd = p.nodeinfo[sd.y];
                    float vx = ns.x - nd.x, vy = ns.y - nd.y, vz = ns.z - nd.z;
                    float len = sqrtf(vx * vx + vy * vy + vz * vz);
                    int pkd = __float_as_int(nd.w);
                    int cd = pkd & 255;
                    int g = pkd >> 8;

                    float t = len * RSTEP;
                    int i1 = (int)floorf(t);
                    int i0 = i1 - 1;
                    float d1 = t - (float)(i1 + 1);
                    float d0 = d1 + 1.0f;
                    float b1v = (i1 <= 9) ? bval(d1) : 0.0f;
                    float b0v = (i0 >= 0) ? bval(d0) : 0.0f;
                    int i1c = min(max(i1, 0), 9);
                    int i0c = min(max(i0, 0), 9);

                    float sk0 = b0v * sh.e.w1k[i0c * 33 + lane]      + b1v * sh.e.w1k[i1c * 33 + lane];
                    float sk1 = b0v * sh.e.w1k[i0c * 33 + lane + 16] + b1v * sh.e.w1k[i1c * 33 + lane + 16];
                    float sv0 = b0v * sh.e.w1v[i0c * 33 + lane]      + b1v * sh.e.w1v[i1c * 33 + lane];
                    float sv1 = b0v * sh.e.w1v[i0c * 33 + lane + 16] + b1v * sh.e.w1v[i1c * 33 + lane + 16];
                    sh.e.hk[grp * 36 + lane]      = silu_n(sk0 * INV_SQRT10);
                    sh.e.hk[grp * 36 + lane + 16] = silu_n(sk1 * INV_SQRT10);
                    sh.e.hv[grp * 36 + lane]      = silu_n(sv0 * INV_SQRT10);
                    sh.e.hv[grp * 36 + lane + 16] = silu_n(sv1 * INV_SQRT10);

                    const float4* hpk = (const float4*)&sh.e.hk[grp * 36];
                    const float4* hpv = (const float4*)&sh.e.hv[grp * 36];
                    const float4* bks = (const float4*)&sh.e.Bk [lane * 36];
                    const float4* b0s = (const float4*)&sh.e.Bv0[lane * 36];
                    const float4* b1s = (const float4*)&sh.e.Bv1[lane * 36];
                    float k0 = 0.0f, v0 = 0.0f, s1v = 0.0f;
#pragma unroll
                    for (int mq = 0; mq < 8; ++mq) {
                        float4 h4 = hpk[mq];
                        float4 a  = bks[mq];
                        k0 += h4.x * a.x + h4.y * a.y + h4.z * a.z + h4.w * a.w;
                        float4 g4 = hpv[mq];
                        float4 a0 = b0s[mq];
                        float4 a1 = b1s[mq];
                        v0  += g4.x * a0.x + g4.y * a0.y + g4.z * a0.z + g4.w * a0.w;
                        s1v += g4.x * a1.x + g4.y * a1.y + g4.z * a1.z + g4.w * a1.w;
                    }
                    float pqk = p.qa[cd * 16 + lane] * k0;
#pragma unroll
                    for (int off = 1; off < 16; off <<= 1) pqk += __shfl_xor(pqk, off, 16);

                    p.vsbuf[idx * 16 + lane] = make_float2(v0, s1v);
                    if (lane == 0) {
                        float cutoff = sus_f(10.0f * (1.0f - len * (1.0f / 6.0f)));
                        float ev = cutoff * __expf(pqk);
                        atomicAdd(&p.zbuf[sd.y], ev);
                        float il = SQRT3 / len;
                        p.geomexp[idx] = make_float4(vx * il, vy * il, vz * il, ev);
                        p.pkbuf[idx] = sd.y | (g << 14);
                    }
                } else {
                    p.vsbuf[idx * 16 + lane] = make_float2(0.0f, 0.0f);
                    if (lane == 0) {
                        p.geomexp[idx] = make_float4(0.0f, 0.0f, 0.0f, 0.0f);
                        p.pkbuf[idx] = 0;
                    }
                }
            }
        }
    }
    grid.sync();

    // ---------- phase 5: accumulate into per-graph LDS, write partials ----------
    int nacc = (G < NACC_MAX) ? G : NACC_MAX;
    if (b < nacc) {
        __syncthreads();
        for (int i = tid; i < N_GRAPHS * 68; i += NTHR) sh.acc.a[i] = 0.0f;
        __syncthreads();
        for (int e = b * 16 + grp; e < ptot; e += nacc * 16) {
            float4 ge = p.geomexp[e];
            int pk = p.pkbuf[e];
            float2 vs = p.vsbuf[e * 16 + lane];
            int dst = pk & 16383;
            int g = pk >> 14;
            float z = p.zbuf[dst];
            if (z == 0.0f) z = 1.0f;
            float att = sqrtf(__fdividef(ge.w, z));
            float v0 = vs.x * att;
            float s1v = vs.y * att;
            float* row = &sh.acc.a[g * 68];
            atomicAdd(&row[lane], v0);
            atomicAdd(&row[16 + lane * 3 + 0], s1v * ge.x);
            atomicAdd(&row[16 + lane * 3 + 1], s1v * ge.y);
            atomicAdd(&row[16 + lane * 3 + 2], s1v * ge.z);
        }
        __syncthreads();
        for (int i = tid; i < N_GRAPHS * 64; i += NTHR)
            p.partial[b * (N_GRAPHS * 64) + i] = sh.acc.a[(i >> 6) * 68 + (i & 63)];
    }
    grid.sync();

    // ---------- phase 6: final reduce + mean ----------
    for (int g = b; g < N_GRAPHS; g += G) {
        __syncthreads();
        int c = tid & 63, q = tid >> 6;   // q in 0..3
        float s = 0.0f;
        for (int bb = q; bb < nacc; bb += 4) s += p.partial[bb * (N_GRAPHS * 64) + g * 64 + c];
        sh.acc.a[q * 64 + c] = s;
        __syncthreads();
        if (q == 0) {
            float tot = sh.acc.a[c] + sh.acc.a[64 + c] + sh.acc.a[128 + c] + sh.acc.a[192 + c];
            int lo = 0, hi = N_NODES;
            while (lo < hi) { int m = (lo + hi) >> 1; if (p.batch[m] < g) lo = m + 1; else hi = m; }
            int st = lo;
            lo = st; hi = N_NODES;
            while (lo < hi) { int m = (lo + hi) >> 1; if (p.batch[m] <= g) lo = m + 1; else hi = m; }
            int cnt = lo - st;
            if (cnt < 1) cnt = 1;
            p.out[g * 64 + c] = tot / (float)cnt;
        }
    }
}

extern "C" void kernel_launch(void* const* d_in, const int* in_sizes, int n_in,
                              void* d_out, int out_size, void* d_ws, size_t ws_size,
                              hipStream_t stream) {
    float* ws = (float*)d_ws;
    Params prm;
    prm.pos       = (const float*)d_in[0];
    prm.z_table   = (const float*)d_in[1];
    prm.mol_table = (const float*)d_in[2];
    prm.Wq        = (const float*)d_in[3];
    prm.W1k       = (const float*)d_in[4];
    prm.W2k       = (const float*)d_in[5];
    prm.W1v       = (const float*)d_in[6];
    prm.W2v       = (const float*)d_in[7];
    prm.Wa        = (const float*)d_in[8];
    // d_in[9] = Wb: unused (q1 == 0 in the reference)
    prm.xarr  = (const int*)d_in[10];
    prm.molid = (const int*)d_in[11];
    prm.esrc  = (const int*)d_in[12];
    prm.edst  = (const int*)d_in[13];
    prm.batch = (const int*)d_in[14];
    prm.out   = (float*)d_out;

    prm.geomexp  = (float4*)ws;                  // 93440 f4  -> 373760 floats
    prm.nodeinfo = (float4*)(ws + 373760);       // 64000
    prm.BkT      = ws + 437760;                  // 102400
    prm.Bv0T     = ws + 540160;                  // 102400
    prm.Bv1T     = ws + 642560;                  // 102400
    prm.qa       = ws + 744960;                  // 3200
    prm.zbuf     = ws + 748160;                  // 16000
    prm.meta     = (int*)(ws + 764160);          // 1024
    prm.partial  = ws + 765184;                  // 256*4096 = 1048576
    prm.vsbuf    = (float2*)(ws + 1813760);      // 93440*16 f2 = 2990080
    prm.spair    = (int2*)(ws + 4803840);        // 93440 int2 = 186880
    prm.csbuf    = (int*)(ws + 4990720);         // 80000
    prm.hist     = (int*)(ws + 5070720);         // 313*200 = 62600
    prm.sbase_g  = (int*)(ws + 5133320);         // 62600
    prm.pkbuf    = (int*)(ws + 5195920);         // 93440   (~21.2 MB total)

    int nb = 0;
    hipOccupancyMaxActiveBlocksPerMultiprocessor(&nb, fused, NTHR, 0);
    if (nb < 1) nb = 1;
    int ncu = 0;
    int dev = 0;
    hipGetDevice(&dev);
    hipDeviceGetAttribute(&ncu, hipDeviceAttributeMultiprocessorCount, dev);
    if (ncu < 1) ncu = 256;
    long long cap = (long long)nb * ncu;
    int G = (cap > 1024) ? 1024 : (int)cap;

    void* args[] = { &prm };
    hipLaunchCooperativeKernel((void*)fused, dim3(G), dim3(NTHR), args, 0, stream);
}

// Round 12
// 143.684 us; speedup vs baseline: 3.0267x; 3.0267x over previous
//
#include <hip/hip_runtime.h>
#include <hip/hip_bf16.h>

#define N_NODES 16000
#define N_EDGES 80000
#define N_GRAPHS 64

#define SILU_NORM 1.679177f
#define SMOOTH_C (1.14136f * 7.38905609893065f)   // 1.14136*e^2
#define SQRT10 3.16227766016838f
#define INV_SQRT10 0.316227766016838f
#define SQRT3 1.7320508075688772f
#define QK_NORM 0.04419417382415922f              // 1/sqrt(2*16*16)
#define SCALE_B 0.02209708691207961f              // (1/8)*(1/sqrt(32))
#define RSTEP (11.0f / 6.0f)
#define BC (SMOOTH_C * SQRT10)

#define NACC 128
#define NB_EDGE 1460
#define PTOT_MAX (NB_EDGE * 64)                   // 93440
#define NBLK_SORT 157                             // ceil(80000/512)

// meta (ints): cnt[0..199], poff[400..600], ptot[601]

__device__ __forceinline__ float sus_f(float x) {
    return x > 0.0f ? __expf(-__fdividef(1.0f, x)) : 0.0f;
}

__device__ __forceinline__ float bval(float d) {
    float pd = 1.0f + d, md = 1.0f - d;
    float e = __expf(-(__fdividef(1.0f, pd) + __fdividef(1.0f, md)));
    return (pd > 0.0f && md > 0.0f) ? BC * e : 0.0f;
}

__device__ __forceinline__ float silu_n(float s) {
    return __fdividef(SILU_NORM * s, 1.0f + __expf(-s));
}

// Fused front-end, 254 blocks x 512 threads:
//   blocks 0..156   : nodeinfo pack + zbuf zero + per-block combo histogram
//                     (block 0 also zeroes gacc + done)
//   blocks 157..252 : B-table builds (3 tables x 32 m-rows)
//   block  253      : qa table
__global__ void prep_kernel(const float* __restrict__ pos,
                            const int* __restrict__ xarr, const int* __restrict__ molid,
                            const int* __restrict__ batch, const int* __restrict__ esrc,
                            const float* __restrict__ z_table,
                            const float* __restrict__ mol_table,
                            const float* __restrict__ Wq, const float* __restrict__ Wa,
                            const float* __restrict__ W2k, const float* __restrict__ W2v,
                            float4* __restrict__ nodeinfo, float* __restrict__ zbuf,
                            int* __restrict__ csbuf, int* __restrict__ hist,
                            float* __restrict__ BkT, float* __restrict__ Bv0T,
                            float* __restrict__ Bv1T, float* __restrict__ qa,
                            float* __restrict__ gacc, int* __restrict__ done) {
    __shared__ int h[200];
    __shared__ float zt[4800];
    __shared__ float mt[32];
    __shared__ float wqa[1024];
    int b = blockIdx.x;
    int tid = threadIdx.x;   // 512

    if (b < NBLK_SORT) {
        if (tid < 200) h[tid] = 0;
        __syncthreads();
        int gid = b * 512 + tid;
        if (gid < N_NODES) {
            int combo = xarr[gid] * 2 + molid[gid];
            int pk = combo | (batch[gid] << 8);
            nodeinfo[gid] = make_float4(pos[3 * gid], pos[3 * gid + 1], pos[3 * gid + 2],
                                        __int_as_float(pk));
            zbuf[gid] = 0.0f;
        }
        if (gid < N_EDGES) {
            int s = esrc[gid];
            int cs = xarr[s] * 2 + molid[s];
            csbuf[gid] = cs;
            atomicAdd(&h[cs], 1);
        }
        if (b == 0) {
            for (int i = tid; i < N_GRAPHS * 64; i += 512) gacc[i] = 0.0f;
            if (tid == 0) *done = 0;
        }
        __syncthreads();
        if (tid < 200) hist[b * 200 + tid] = h[tid];
        return;
    }

    // table-builder blocks
    for (int i = tid; i < 4800; i += 512) zt[i] = z_table[i];
    if (tid < 32) mt[tid] = mol_table[tid];
    int tb = b - NBLK_SORT;      // 0..96
    if (tb == 96) {
        for (int o = tid; o < 1024; o += 512) {
            int u = o >> 4, w = o & 15;
            float s = 0.0f;
#pragma unroll
            for (int v = 0; v < 16; ++v) s += Wq[u * 16 + v] * Wa[v * 16 + w];
            wqa[o] = s;
        }
        __syncthreads();
        for (int o = tid; o < 200 * 16; o += 512) {
            int combo = o >> 4, w = o & 15;
            int elem = combo >> 1, mol = combo & 1;
            float s = 0.0f;
#pragma unroll
            for (int u = 0; u < 48; ++u) s += zt[elem * 48 + u] * wqa[u * 16 + w];
#pragma unroll
            for (int u = 0; u < 16; ++u) s += mt[mol * 16 + u] * wqa[(48 + u) * 16 + w];
            qa[combo * 16 + w] = s * 0.125f * QK_NORM;
        }
        return;
    }
    int t = tb >> 5;         // 0=k, 1=v0, 2=v1
    int m = tb & 31;
    int w = tid & 15;
    const float* src = (t == 0) ? (W2k + m * 2048)
                     : (t == 1) ? (W2v + m * 2048)
                                : (W2v + m * 2048 + 1024);
    float w2c[64];
#pragma unroll
    for (int u = 0; u < 64; ++u) w2c[u] = src[u * 16 + w];
    __syncthreads();
    float* dstT = (t == 0) ? BkT : (t == 1) ? Bv0T : Bv1T;
    for (int o = tid; o < 200 * 16; o += 512) {   // 512%16==0 keeps w == o&15
        int combo = o >> 4;
        int elem = combo >> 1, mol = combo & 1;
        const float* f = &zt[elem * 48];
        float s = 0.0f;
#pragma unroll
        for (int u = 0; u < 48; ++u) s += f[u] * w2c[u];
        const float* mm = &mt[mol * 16];
#pragma unroll
        for (int u = 0; u < 16; ++u) s += mm[u] * w2c[48 + u];
        dstT[combo * 512 + w * 32 + m] = s * SCALE_B;
    }
}

// Scatter with INLINE redundant scan (each block recomputes offsets + its own
// per-combo base from hist). Block 0 publishes meta for edge/acc kernels.
__global__ void scatter_kernel(const int* __restrict__ csbuf,
                               const int* __restrict__ esrc, const int* __restrict__ edst,
                               const int* __restrict__ hist,
                               int* __restrict__ meta, int2* __restrict__ spair) {
    __shared__ int scnt[200];
    __shared__ int sbase[200];
    __shared__ int soff[201];
    __shared__ int cnt2[200];
    int b = blockIdx.x;
    int tid = threadIdx.x;   // 512
    if (tid < 200) {
        int tot = 0, mine = 0;
        for (int b2 = 0; b2 < NBLK_SORT; ++b2) {
            int hv = hist[b2 * 200 + tid];
            if (b2 < b) mine += hv;
            tot += hv;
        }
        scnt[tid] = tot;
        sbase[tid] = mine;
        cnt2[tid] = 0;
    }
    __syncthreads();
    if (tid == 0) {
        int acc = 0;
        for (int c = 0; c < 200; ++c) { soff[c] = acc; acc += (scnt[c] + 63) & ~63; }
        soff[200] = acc;
    }
    __syncthreads();
    if (tid < 200) sbase[tid] += soff[tid];
    if (b == 0) {
        if (tid < 200) meta[tid] = scnt[tid];
        if (tid < 201) meta[400 + tid] = soff[tid];
        if (tid == 0) meta[601] = soff[200];
    }
    __syncthreads();
    int e = b * 512 + tid;
    if (e < N_EDGES) {
        int cs = csbuf[e];
        int r = atomicAdd(&cnt2[cs], 1);     // LDS atomic: block-local
        spair[sbase[cs] + r] = make_int2(esrc[e], edst[e]);
    }
}

// Bucketed edge pass: one combo per block, tables staged in LDS (stride 36).
__global__ void edge_kernel(const int2* __restrict__ spair,
                            const float4* __restrict__ nodeinfo,
                            const float* __restrict__ W1k, const float* __restrict__ W1v,
                            const float* __restrict__ BkT, const float* __restrict__ Bv0T,
                            const float* __restrict__ Bv1T, const float* __restrict__ qa,
                            const int* __restrict__ meta,
                            float4* __restrict__ geomexp, int* __restrict__ pkbuf,
                            float2* __restrict__ vsbuf, float* __restrict__ zbuf) {
    __shared__ float Bk_s[16 * 36], Bv0_s[16 * 36], Bv1_s[16 * 36];
    __shared__ float w1k_s[10 * 33], w1v_s[10 * 33];
    __shared__ float hk[16][36], hv[16][36];
    int b = blockIdx.x;
    int base = b * 64;
    int ptot = meta[601];
    if (base >= ptot) return;
    const int* poff = meta + 400;
    int lo = 0, hi = 200;
    while (lo < hi) { int m = (lo + hi) >> 1; if (poff[m + 1] <= base) lo = m + 1; else hi = m; }
    int combo = lo;
    int vend = poff[combo] + meta[combo];    // first invalid slot in this bucket
    int tid = threadIdx.x, lane = tid & 15, grp = tid >> 4;
    for (int o = tid; o < 512; o += 256) {
        int w = o >> 5, m = o & 31;
        Bk_s [w * 36 + m] = BkT [combo * 512 + o];
        Bv0_s[w * 36 + m] = Bv0T[combo * 512 + o];
        Bv1_s[w * 36 + m] = Bv1T[combo * 512 + o];
    }
    for (int o = tid; o < 330; o += 256) {
        int i = o / 33, ch = o % 33;
        if (ch < 32) {
            w1k_s[o] = W1k[i * 32 + ch];
            w1v_s[o] = W1v[i * 32 + ch];
        }
    }
    __syncthreads();
#pragma unroll
    for (int it = 0; it < 4; ++it) {
        int idx = base + it * 16 + grp;
        if (idx < vend) {
            int2 sd = spair[idx];
            float4 ns = nodeinfo[sd.x];
            float4 nd = nodeinfo[sd.y];
            float vx = ns.x - nd.x, vy = ns.y - nd.y, vz = ns.z - nd.z;
            float len = sqrtf(vx * vx + vy * vy + vz * vz);
            int pkd = __float_as_int(nd.w);
            int cd = pkd & 255;
            int g = pkd >> 8;

            float t = len * RSTEP;
            int i1 = (int)floorf(t);
            int i0 = i1 - 1;
            float d1 = t - (float)(i1 + 1);
            float d0 = d1 + 1.0f;
            float b1v = (i1 <= 9) ? bval(d1) : 0.0f;
            float b0v = (i0 >= 0) ? bval(d0) : 0.0f;
            int i1c = min(max(i1, 0), 9);
            int i0c = min(max(i0, 0), 9);

            float sk0 = b0v * w1k_s[i0c * 33 + lane]      + b1v * w1k_s[i1c * 33 + lane];
            float sk1 = b0v * w1k_s[i0c * 33 + lane + 16] + b1v * w1k_s[i1c * 33 + lane + 16];
            float sv0 = b0v * w1v_s[i0c * 33 + lane]      + b1v * w1v_s[i1c * 33 + lane];
            float sv1 = b0v * w1v_s[i0c * 33 + lane + 16] + b1v * w1v_s[i1c * 33 + lane + 16];
            hk[grp][lane]      = silu_n(sk0 * INV_SQRT10);
            hk[grp][lane + 16] = silu_n(sk1 * INV_SQRT10);
            hv[grp][lane]      = silu_n(sv0 * INV_SQRT10);
            hv[grp][lane + 16] = silu_n(sv1 * INV_SQRT10);

            const float4* hpk = (const float4*)&hk[grp][0];
            const float4* hpv = (const float4*)&hv[grp][0];
            const float4* bks = (const float4*)&Bk_s [lane * 36];
            const float4* b0s = (const float4*)&Bv0_s[lane * 36];
            const float4* b1s = (const float4*)&Bv1_s[lane * 36];
            float k0 = 0.0f, v0 = 0.0f, s1v = 0.0f;
#pragma unroll
            for (int mq = 0; mq < 8; ++mq) {
                float4 h4 = hpk[mq];
                float4 a  = bks[mq];
                k0 += h4.x * a.x + h4.y * a.y + h4.z * a.z + h4.w * a.w;
                float4 g4 = hpv[mq];
                float4 a0 = b0s[mq];
                float4 a1 = b1s[mq];
                v0  += g4.x * a0.x + g4.y * a0.y + g4.z * a0.z + g4.w * a0.w;
                s1v += g4.x * a1.x + g4.y * a1.y + g4.z * a1.z + g4.w * a1.w;
            }
            float p = qa[cd * 16 + lane] * k0;
#pragma unroll
            for (int off = 1; off < 16; off <<= 1) p += __shfl_xor(p, off, 16);

            vsbuf[idx * 16 + lane] = make_float2(v0, s1v);
            if (lane == 0) {
                float cutoff = sus_f(10.0f * (1.0f - len * (1.0f / 6.0f)));
                float ev = cutoff * __expf(p);
                atomicAdd(&zbuf[sd.y], ev);
                float il = SQRT3 / len;
                geomexp[idx] = make_float4(vx * il, vy * il, vz * il, ev);
                pkbuf[idx] = sd.y | (g << 14);
            }
        } else {
            vsbuf[idx * 16 + lane] = make_float2(0.0f, 0.0f);
            if (lane == 0) {
                geomexp[idx] = make_float4(0.0f, 0.0f, 0.0f, 0.0f);
                pkbuf[idx] = 0;
            }
        }
    }
}

// Accumulate into per-graph LDS, flush tile via global atomics to gacc;
// last finishing block divides by per-graph counts and writes out.
__global__ void __launch_bounds__(1024)
acc_kernel(const float4* __restrict__ geomexp, const int* __restrict__ pkbuf,
           const float2* __restrict__ vsbuf, const float* __restrict__ zbuf,
           const int* __restrict__ meta, const int* __restrict__ batch,
           float* __restrict__ gacc, int* __restrict__ done,
           float* __restrict__ out) {
    __shared__ float acc[N_GRAPHS * 68];
    int tid = threadIdx.x;
    int lane = tid & 15;
    int grp = tid >> 4;
    int ptot = meta[601];
    for (int i = tid; i < N_GRAPHS * 68; i += 1024) acc[i] = 0.0f;
    __syncthreads();
    int gid = blockIdx.x * 64 + grp;
    for (int e = gid; e < ptot; e += NACC * 64) {
        float4 ge = geomexp[e];
        int pk = pkbuf[e];
        float2 vs = vsbuf[e * 16 + lane];
        int dst = pk & 16383;
        int g = pk >> 14;
        float z = zbuf[dst];
        if (z == 0.0f) z = 1.0f;
        float att = sqrtf(__fdividef(ge.w, z));
        float v0 = vs.x * att;
        float s1v = vs.y * att;
        float* row = &acc[g * 68];
        atomicAdd(&row[lane], v0);
        atomicAdd(&row[16 + lane * 3 + 0], s1v * ge.x);
        atomicAdd(&row[16 + lane * 3 + 1], s1v * ge.y);
        atomicAdd(&row[16 + lane * 3 + 2], s1v * ge.z);
    }
    __syncthreads();
    for (int i = tid; i < N_GRAPHS * 64; i += 1024)
        atomicAdd(&gacc[i], acc[(i >> 6) * 68 + (i & 63)]);   // non-returning, distributed

    // last-block finalize (tiny: 4096 reads + 4096 writes)
    __threadfence();
    __shared__ int amlast;
    if (tid == 0) amlast = (atomicAdd(done, 1) == NACC - 1) ? 1 : 0;
    __syncthreads();
    if (!amlast) return;
    __threadfence();
    __shared__ int cntg[N_GRAPHS];
    if (tid < N_GRAPHS) {
        int g = tid;
        int lo = 0, hi = N_NODES;
        while (lo < hi) { int m = (lo + hi) >> 1; if (batch[m] < g) lo = m + 1; else hi = m; }
        int st = lo;
        lo = st; hi = N_NODES;
        while (lo < hi) { int m = (lo + hi) >> 1; if (batch[m] <= g) lo = m + 1; else hi = m; }
        int c = lo - st;
        cntg[g] = (c < 1) ? 1 : c;
    }
    __syncthreads();
    for (int o = tid; o < N_GRAPHS * 64; o += 1024)
        out[o] = gacc[o] / (float)cntg[o >> 6];
}

extern "C" void kernel_launch(void* const* d_in, const int* in_sizes, int n_in,
                              void* d_out, int out_size, void* d_ws, size_t ws_size,
                              hipStream_t stream) {
    const float* pos       = (const float*)d_in[0];
    const float* z_table   = (const float*)d_in[1];
    const float* mol_table = (const float*)d_in[2];
    const float* Wq        = (const float*)d_in[3];
    const float* W1k       = (const float*)d_in[4];
    const float* W2k       = (const float*)d_in[5];
    const float* W1v       = (const float*)d_in[6];
    const float* W2v       = (const float*)d_in[7];
    const float* Wa        = (const float*)d_in[8];
    // d_in[9] = Wb: unused (q1 == 0 in the reference)
    const int* x     = (const int*)d_in[10];
    const int* molid = (const int*)d_in[11];
    const int* esrc  = (const int*)d_in[12];
    const int* edst  = (const int*)d_in[13];
    const int* batch = (const int*)d_in[14];
    float* out = (float*)d_out;

    float* ws = (float*)d_ws;
    float4* geomexp  = (float4*)ws;                         // 93440 f4 -> 373760 floats
    float4* nodeinfo = (float4*)(ws + 373760);              // 64000
    float*  BkT      = ws + 437760;                         // 102400
    float*  Bv0T     = ws + 540160;                         // 102400
    float*  Bv1T     = ws + 642560;                         // 102400
    float*  qa       = ws + 744960;                         // 3200
    float*  zbuf     = ws + 748160;                         // 16000
    int*    meta     = (int*)(ws + 764160);                 // 1024
    float*  gacc     = ws + 765184;                         // 4096
    int*    done     = (int*)(ws + 769280);                 // 16 (padded)
    float2* vsbuf    = (float2*)(ws + 769296);              // 93440*16 f2 = 2990080
    int2*   spair    = (int2*)(ws + 3759376);               // 93440 int2 = 186880
    int*    csbuf    = (int*)(ws + 3946256);                // 80000
    int*    hist     = (int*)(ws + 4026256);                // 157*200 = 31400
    int*    pkbuf    = (int*)(ws + 4057656);                // 93440  (~16.6 MB total)

    prep_kernel<<<NBLK_SORT + 97, 512, 0, stream>>>(pos, x, molid, batch, esrc,
                                                    z_table, mol_table, Wq, Wa, W2k, W2v,
                                                    nodeinfo, zbuf, csbuf, hist,
                                                    BkT, Bv0T, Bv1T, qa, gacc, done);
    scatter_kernel<<<NBLK_SORT, 512, 0, stream>>>(csbuf, esrc, edst, hist, meta, spair);
    edge_kernel<<<NB_EDGE, 256, 0, stream>>>(spair, nodeinfo, W1k, W1v,
                                             BkT, Bv0T, Bv1T, qa, meta,
                                             geomexp, pkbuf, vsbuf, zbuf);
    acc_kernel<<<NACC, 1024, 0, stream>>>(geomexp, pkbuf, vsbuf, zbuf, meta, batch,
                                          gacc, done, out);
}

// Round 13
// 105.546 us; speedup vs baseline: 4.1203x; 1.3613x over previous
//
#include <hip/hip_runtime.h>
#include <hip/hip_bf16.h>

#define N_NODES 16000
#define N_EDGES 80000
#define N_GRAPHS 64

#define SILU_NORM 1.679177f
#define SMOOTH_C (1.14136f * 7.38905609893065f)   // 1.14136*e^2
#define SQRT10 3.16227766016838f
#define INV_SQRT10 0.316227766016838f
#define SQRT3 1.7320508075688772f
#define QK_NORM 0.04419417382415922f              // 1/sqrt(2*16*16)
#define SCALE_B 0.02209708691207961f              // (1/8)*(1/sqrt(32))
#define RSTEP (11.0f / 6.0f)
#define BC (SMOOTH_C * SQRT10)

#define NACC 256
#define NB_EDGE 1460
#define PTOT_MAX (NB_EDGE * 64)                   // 93440
#define NBLK_SORT 157                             // ceil(80000/512)

// meta (ints): cnt[0..199], poff[400..600], ptot[601]

__device__ __forceinline__ float sus_f(float x) {
    return x > 0.0f ? __expf(-__fdividef(1.0f, x)) : 0.0f;
}

__device__ __forceinline__ float bval(float d) {
    float pd = 1.0f + d, md = 1.0f - d;
    float e = __expf(-(__fdividef(1.0f, pd) + __fdividef(1.0f, md)));
    return (pd > 0.0f && md > 0.0f) ? BC * e : 0.0f;
}

__device__ __forceinline__ float silu_n(float s) {
    return __fdividef(SILU_NORM * s, 1.0f + __expf(-s));
}

// Fused front-end, 254 blocks x 512 threads:
//   blocks 0..156   : nodeinfo pack + zbuf zero + per-block combo histogram
//   blocks 157..252 : B-table builds (3 tables x 32 m-rows)
//   block  253      : qa table
__global__ void prep_kernel(const float* __restrict__ pos,
                            const int* __restrict__ xarr, const int* __restrict__ molid,
                            const int* __restrict__ batch, const int* __restrict__ esrc,
                            const float* __restrict__ z_table,
                            const float* __restrict__ mol_table,
                            const float* __restrict__ Wq, const float* __restrict__ Wa,
                            const float* __restrict__ W2k, const float* __restrict__ W2v,
                            float4* __restrict__ nodeinfo, float* __restrict__ zbuf,
                            int* __restrict__ csbuf, int* __restrict__ hist,
                            float* __restrict__ BkT, float* __restrict__ Bv0T,
                            float* __restrict__ Bv1T, float* __restrict__ qa) {
    __shared__ int h[200];
    __shared__ float zt[4800];
    __shared__ float mt[32];
    __shared__ float wqa[1024];
    int b = blockIdx.x;
    int tid = threadIdx.x;   // 512

    if (b < NBLK_SORT) {
        if (tid < 200) h[tid] = 0;
        __syncthreads();
        int gid = b * 512 + tid;
        if (gid < N_NODES) {
            int combo = xarr[gid] * 2 + molid[gid];
            int pk = combo | (batch[gid] << 8);
            nodeinfo[gid] = make_float4(pos[3 * gid], pos[3 * gid + 1], pos[3 * gid + 2],
                                        __int_as_float(pk));
            zbuf[gid] = 0.0f;
        }
        if (gid < N_EDGES) {
            int s = esrc[gid];
            int cs = xarr[s] * 2 + molid[s];
            csbuf[gid] = cs;
            atomicAdd(&h[cs], 1);
        }
        __syncthreads();
        if (tid < 200) hist[b * 200 + tid] = h[tid];
        return;
    }

    // table-builder blocks
    for (int i = tid; i < 4800; i += 512) zt[i] = z_table[i];
    if (tid < 32) mt[tid] = mol_table[tid];
    int tb = b - NBLK_SORT;      // 0..96
    if (tb == 96) {
        for (int o = tid; o < 1024; o += 512) {
            int u = o >> 4, w = o & 15;
            float s = 0.0f;
#pragma unroll
            for (int v = 0; v < 16; ++v) s += Wq[u * 16 + v] * Wa[v * 16 + w];
            wqa[o] = s;
        }
        __syncthreads();
        for (int o = tid; o < 200 * 16; o += 512) {
            int combo = o >> 4, w = o & 15;
            int elem = combo >> 1, mol = combo & 1;
            float s = 0.0f;
#pragma unroll
            for (int u = 0; u < 48; ++u) s += zt[elem * 48 + u] * wqa[u * 16 + w];
#pragma unroll
            for (int u = 0; u < 16; ++u) s += mt[mol * 16 + u] * wqa[(48 + u) * 16 + w];
            qa[combo * 16 + w] = s * 0.125f * QK_NORM;
        }
        return;
    }
    int t = tb >> 5;         // 0=k, 1=v0, 2=v1
    int m = tb & 31;
    int w = tid & 15;
    const float* src = (t == 0) ? (W2k + m * 2048)
                     : (t == 1) ? (W2v + m * 2048)
                                : (W2v + m * 2048 + 1024);
    float w2c[64];
#pragma unroll
    for (int u = 0; u < 64; ++u) w2c[u] = src[u * 16 + w];
    __syncthreads();
    float* dstT = (t == 0) ? BkT : (t == 1) ? Bv0T : Bv1T;
    for (int o = tid; o < 200 * 16; o += 512) {   // 512%16==0 keeps w == o&15
        int combo = o >> 4;
        int elem = combo >> 1, mol = combo & 1;
        const float* f = &zt[elem * 48];
        float s = 0.0f;
#pragma unroll
        for (int u = 0; u < 48; ++u) s += f[u] * w2c[u];
        const float* mm = &mt[mol * 16];
#pragma unroll
        for (int u = 0; u < 16; ++u) s += mm[u] * w2c[48 + u];
        dstT[combo * 512 + w * 32 + m] = s * SCALE_B;
    }
}

// Scatter with INLINE redundant scan (each block recomputes offsets + its own
// per-combo base from hist). Block 0 publishes meta for edge/acc kernels.
__global__ void scatter_kernel(const int* __restrict__ csbuf,
                               const int* __restrict__ esrc, const int* __restrict__ edst,
                               const int* __restrict__ hist,
                               int* __restrict__ meta, int2* __restrict__ spair) {
    __shared__ int scnt[200];
    __shared__ int sbase[200];
    __shared__ int soff[201];
    __shared__ int cnt2[200];
    int b = blockIdx.x;
    int tid = threadIdx.x;   // 512
    if (tid < 200) {
        int tot = 0, mine = 0;
        for (int b2 = 0; b2 < NBLK_SORT; ++b2) {
            int hv = hist[b2 * 200 + tid];
            if (b2 < b) mine += hv;
            tot += hv;
        }
        scnt[tid] = tot;
        sbase[tid] = mine;
        cnt2[tid] = 0;
    }
    __syncthreads();
    if (tid == 0) {
        int acc = 0;
        for (int c = 0; c < 200; ++c) { soff[c] = acc; acc += (scnt[c] + 63) & ~63; }
        soff[200] = acc;
    }
    __syncthreads();
    if (tid < 200) sbase[tid] += soff[tid];
    if (b == 0) {
        if (tid < 200) meta[tid] = scnt[tid];
        if (tid < 201) meta[400 + tid] = soff[tid];
        if (tid == 0) meta[601] = soff[200];
    }
    __syncthreads();
    int e = b * 512 + tid;
    if (e < N_EDGES) {
        int cs = csbuf[e];
        int r = atomicAdd(&cnt2[cs], 1);     // LDS atomic: block-local
        spair[sbase[cs] + r] = make_int2(esrc[e], edst[e]);
    }
}

// Bucketed edge pass: one combo per block, tables staged in LDS (stride 36).
__global__ void edge_kernel(const int2* __restrict__ spair,
                            const float4* __restrict__ nodeinfo,
                            const float* __restrict__ W1k, const float* __restrict__ W1v,
                            const float* __restrict__ BkT, const float* __restrict__ Bv0T,
                            const float* __restrict__ Bv1T, const float* __restrict__ qa,
                            const int* __restrict__ meta,
                            float4* __restrict__ geomexp, int* __restrict__ pkbuf,
                            float2* __restrict__ vsbuf, float* __restrict__ zbuf) {
    __shared__ float Bk_s[16 * 36], Bv0_s[16 * 36], Bv1_s[16 * 36];
    __shared__ float w1k_s[10 * 33], w1v_s[10 * 33];
    __shared__ float hk[16][36], hv[16][36];
    int b = blockIdx.x;
    int base = b * 64;
    int ptot = meta[601];
    if (base >= ptot) return;
    const int* poff = meta + 400;
    int lo = 0, hi = 200;
    while (lo < hi) { int m = (lo + hi) >> 1; if (poff[m + 1] <= base) lo = m + 1; else hi = m; }
    int combo = lo;
    int vend = poff[combo] + meta[combo];    // first invalid slot in this bucket
    int tid = threadIdx.x, lane = tid & 15, grp = tid >> 4;
    for (int o = tid; o < 512; o += 256) {
        int w = o >> 5, m = o & 31;
        Bk_s [w * 36 + m] = BkT [combo * 512 + o];
        Bv0_s[w * 36 + m] = Bv0T[combo * 512 + o];
        Bv1_s[w * 36 + m] = Bv1T[combo * 512 + o];
    }
    for (int o = tid; o < 330; o += 256) {
        int i = o / 33, ch = o % 33;
        if (ch < 32) {
            w1k_s[o] = W1k[i * 32 + ch];
            w1v_s[o] = W1v[i * 32 + ch];
        }
    }
    __syncthreads();
#pragma unroll
    for (int it = 0; it < 4; ++it) {
        int idx = base + it * 16 + grp;
        if (idx < vend) {
            int2 sd = spair[idx];
            float4 ns = nodeinfo[sd.x];
            float4 nd = nodeinfo[sd.y];
            float vx = ns.x - nd.x, vy = ns.y - nd.y, vz = ns.z - nd.z;
            float len = sqrtf(vx * vx + vy * vy + vz * vz);
            int pkd = __float_as_int(nd.w);
            int cd = pkd & 255;
            int g = pkd >> 8;

            float t = len * RSTEP;
            int i1 = (int)floorf(t);
            int i0 = i1 - 1;
            float d1 = t - (float)(i1 + 1);
            float d0 = d1 + 1.0f;
            float b1v = (i1 <= 9) ? bval(d1) : 0.0f;
            float b0v = (i0 >= 0) ? bval(d0) : 0.0f;
            int i1c = min(max(i1, 0), 9);
            int i0c = min(max(i0, 0), 9);

            float sk0 = b0v * w1k_s[i0c * 33 + lane]      + b1v * w1k_s[i1c * 33 + lane];
            float sk1 = b0v * w1k_s[i0c * 33 + lane + 16] + b1v * w1k_s[i1c * 33 + lane + 16];
            float sv0 = b0v * w1v_s[i0c * 33 + lane]      + b1v * w1v_s[i1c * 33 + lane];
            float sv1 = b0v * w1v_s[i0c * 33 + lane + 16] + b1v * w1v_s[i1c * 33 + lane + 16];
            hk[grp][lane]      = silu_n(sk0 * INV_SQRT10);
            hk[grp][lane + 16] = silu_n(sk1 * INV_SQRT10);
            hv[grp][lane]      = silu_n(sv0 * INV_SQRT10);
            hv[grp][lane + 16] = silu_n(sv1 * INV_SQRT10);

            const float4* hpk = (const float4*)&hk[grp][0];
            const float4* hpv = (const float4*)&hv[grp][0];
            const float4* bks = (const float4*)&Bk_s [lane * 36];
            const float4* b0s = (const float4*)&Bv0_s[lane * 36];
            const float4* b1s = (const float4*)&Bv1_s[lane * 36];
            float k0 = 0.0f, v0 = 0.0f, s1v = 0.0f;
#pragma unroll
            for (int mq = 0; mq < 8; ++mq) {
                float4 h4 = hpk[mq];
                float4 a  = bks[mq];
                k0 += h4.x * a.x + h4.y * a.y + h4.z * a.z + h4.w * a.w;
                float4 g4 = hpv[mq];
                float4 a0 = b0s[mq];
                float4 a1 = b1s[mq];
                v0  += g4.x * a0.x + g4.y * a0.y + g4.z * a0.z + g4.w * a0.w;
                s1v += g4.x * a1.x + g4.y * a1.y + g4.z * a1.z + g4.w * a1.w;
            }
            float p = qa[cd * 16 + lane] * k0;
#pragma unroll
            for (int off = 1; off < 16; off <<= 1) p += __shfl_xor(p, off, 16);

            vsbuf[idx * 16 + lane] = make_float2(v0, s1v);
            if (lane == 0) {
                float cutoff = sus_f(10.0f * (1.0f - len * (1.0f / 6.0f)));
                float ev = cutoff * __expf(p);
                atomicAdd(&zbuf[sd.y], ev);
                float il = SQRT3 / len;
                geomexp[idx] = make_float4(vx * il, vy * il, vz * il, ev);
                pkbuf[idx] = sd.y | (g << 14);
            }
        } else {
            vsbuf[idx * 16 + lane] = make_float2(0.0f, 0.0f);
            if (lane == 0) {
                geomexp[idx] = make_float4(0.0f, 0.0f, 0.0f, 0.0f);
                pkbuf[idx] = 0;
            }
        }
    }
}

// Accumulate: att = sqrt(ev/z), 4 LDS atomics per lane, per-block partials.
// NO device-scope fences (they cost 60-130us on this 8-XCD part).
__global__ void __launch_bounds__(1024)
acc_kernel(const float4* __restrict__ geomexp, const int* __restrict__ pkbuf,
           const float2* __restrict__ vsbuf, const float* __restrict__ zbuf,
           const int* __restrict__ meta, float* __restrict__ partial) {
    __shared__ float acc[N_GRAPHS * 68];
    int tid = threadIdx.x;
    int lane = tid & 15;
    int grp = tid >> 4;
    int ptot = meta[601];
    for (int i = tid; i < N_GRAPHS * 68; i += 1024) acc[i] = 0.0f;
    __syncthreads();
    int gid = blockIdx.x * 64 + grp;
    for (int e = gid; e < ptot; e += NACC * 64) {
        float4 ge = geomexp[e];
        int pk = pkbuf[e];
        float2 vs = vsbuf[e * 16 + lane];
        int dst = pk & 16383;
        int g = pk >> 14;
        float z = zbuf[dst];
        if (z == 0.0f) z = 1.0f;
        float att = sqrtf(__fdividef(ge.w, z));
        float v0 = vs.x * att;
        float s1v = vs.y * att;
        float* row = &acc[g * 68];
        atomicAdd(&row[lane], v0);
        atomicAdd(&row[16 + lane * 3 + 0], s1v * ge.x);
        atomicAdd(&row[16 + lane * 3 + 1], s1v * ge.y);
        atomicAdd(&row[16 + lane * 3 + 2], s1v * ge.z);
    }
    __syncthreads();
    for (int i = tid; i < N_GRAPHS * 64; i += 1024)
        partial[blockIdx.x * (N_GRAPHS * 64) + i] = acc[(i >> 6) * 68 + (i & 63)];
}

__global__ void reduce_kernel(const float* __restrict__ partial,
                              const int* __restrict__ batch,
                              float* __restrict__ out) {
    __shared__ float red[4][64];
    int g = blockIdx.x;
    int c = threadIdx.x & 63;
    int q = threadIdx.x >> 6;
    float s = 0.0f;
    for (int bb = q; bb < NACC; bb += 4) s += partial[bb * (N_GRAPHS * 64) + g * 64 + c];
    red[q][c] = s;
    __syncthreads();
    if (q == 0) {
        float tot = red[0][c] + red[1][c] + red[2][c] + red[3][c];
        int lo = 0, hi = N_NODES;
        while (lo < hi) { int m = (lo + hi) >> 1; if (batch[m] < g) lo = m + 1; else hi = m; }
        int st = lo;
        lo = st; hi = N_NODES;
        while (lo < hi) { int m = (lo + hi) >> 1; if (batch[m] <= g) lo = m + 1; else hi = m; }
        int cnt = lo - st;
        if (cnt < 1) cnt = 1;
        out[g * 64 + c] = tot / (float)cnt;
    }
}

extern "C" void kernel_launch(void* const* d_in, const int* in_sizes, int n_in,
                              void* d_out, int out_size, void* d_ws, size_t ws_size,
                              hipStream_t stream) {
    const float* pos       = (const float*)d_in[0];
    const float* z_table   = (const float*)d_in[1];
    const float* mol_table = (const float*)d_in[2];
    const float* Wq        = (const float*)d_in[3];
    const float* W1k       = (const float*)d_in[4];
    const float* W2k       = (const float*)d_in[5];
    const float* W1v       = (const float*)d_in[6];
    const float* W2v       = (const float*)d_in[7];
    const float* Wa        = (const float*)d_in[8];
    // d_in[9] = Wb: unused (q1 == 0 in the reference)
    const int* x     = (const int*)d_in[10];
    const int* molid = (const int*)d_in[11];
    const int* esrc  = (const int*)d_in[12];
    const int* edst  = (const int*)d_in[13];
    const int* batch = (const int*)d_in[14];
    float* out = (float*)d_out;

    float* ws = (float*)d_ws;
    float4* geomexp  = (float4*)ws;                         // 93440 f4 -> 373760 floats
    float4* nodeinfo = (float4*)(ws + 373760);              // 64000
    float*  BkT      = ws + 437760;                         // 102400
    float*  Bv0T     = ws + 540160;                         // 102400
    float*  Bv1T     = ws + 642560;                         // 102400
    float*  qa       = ws + 744960;                         // 3200
    float*  zbuf     = ws + 748160;                         // 16000
    int*    meta     = (int*)(ws + 764160);                 // 1024
    float*  partial  = ws + 765184;                         // 256*4096 = 1048576
    float2* vsbuf    = (float2*)(ws + 1813760);             // 93440*16 f2 = 2990080
    int2*   spair    = (int2*)(ws + 4803840);               // 93440 int2 = 186880
    int*    csbuf    = (int*)(ws + 4990720);                // 80000
    int*    hist     = (int*)(ws + 5070720);                // 157*200 = 31400
    int*    pkbuf    = (int*)(ws + 5102120);                // 93440  (~20.8 MB total)

    prep_kernel<<<NBLK_SORT + 97, 512, 0, stream>>>(pos, x, molid, batch, esrc,
                                                    z_table, mol_table, Wq, Wa, W2k, W2v,
                                                    nodeinfo, zbuf, csbuf, hist,
                                                    BkT, Bv0T, Bv1T, qa);
    scatter_kernel<<<NBLK_SORT, 512, 0, stream>>>(csbuf, esrc, edst, hist, meta, spair);
    edge_kernel<<<NB_EDGE, 256, 0, stream>>>(spair, nodeinfo, W1k, W1v,
                                             BkT, Bv0T, Bv1T, qa, meta,
                                             geomexp, pkbuf, vsbuf, zbuf);
    acc_kernel<<<NACC, 1024, 0, stream>>>(geomexp, pkbuf, vsbuf, zbuf, meta, partial);
    reduce_kernel<<<N_GRAPHS, 256, 0, stream>>>(partial, batch, out);
}

// Round 14
// 88.041 us; speedup vs baseline: 4.9395x; 1.1988x over previous
//
#include <hip/hip_runtime.h>
#include <hip/hip_bf16.h>

#define N_NODES 16000
#define N_EDGES 80000
#define N_GRAPHS 64

#define SILU_NORM 1.679177f
#define SMOOTH_C (1.14136f * 7.38905609893065f)   // 1.14136*e^2
#define SQRT10 3.16227766016838f
#define INV_SQRT10 0.316227766016838f
#define SQRT3 1.7320508075688772f
#define QK_NORM 0.04419417382415922f              // 1/sqrt(2*16*16)
#define SCALE_B 0.02209708691207961f              // (1/8)*(1/sqrt(32))
#define RSTEP (11.0f / 6.0f)
#define BC (SMOOTH_C * SQRT10)

#define NACC 256
#define NB_EDGE 1460
#define PTOT_MAX (NB_EDGE * 64)                   // 93440
#define NBLK_SORT 157                             // ceil(80000/512)

// meta (ints): cnt[0..199], poff[400..600], ptot[601]

__device__ __forceinline__ float sus_f(float x) {
    return x > 0.0f ? __expf(-__fdividef(1.0f, x)) : 0.0f;
}

__device__ __forceinline__ float bval(float d) {
    float pd = 1.0f + d, md = 1.0f - d;
    float e = __expf(-(__fdividef(1.0f, pd) + __fdividef(1.0f, md)));
    return (pd > 0.0f && md > 0.0f) ? BC * e : 0.0f;
}

__device__ __forceinline__ float silu_n(float s) {
    return __fdividef(SILU_NORM * s, 1.0f + __expf(-s));
}

// Fused front-end, 254 blocks x 512 threads:
//   blocks 0..156   : nodeinfo pack + zbuf zero + per-block combo histogram
//                     (block 0 also zeroes d_out)
//   blocks 157..252 : B-table builds (3 tables x 32 m-rows)
//   block  253      : qa table + per-graph inverse counts
__global__ void prep_kernel(const float* __restrict__ pos,
                            const int* __restrict__ xarr, const int* __restrict__ molid,
                            const int* __restrict__ batch, const int* __restrict__ esrc,
                            const float* __restrict__ z_table,
                            const float* __restrict__ mol_table,
                            const float* __restrict__ Wq, const float* __restrict__ Wa,
                            const float* __restrict__ W2k, const float* __restrict__ W2v,
                            float4* __restrict__ nodeinfo, float* __restrict__ zbuf,
                            int* __restrict__ csbuf, int* __restrict__ hist,
                            float* __restrict__ BkT, float* __restrict__ Bv0T,
                            float* __restrict__ Bv1T, float* __restrict__ qa,
                            float* __restrict__ invc, float* __restrict__ out) {
    __shared__ int h[200];
    __shared__ float zt[4800];
    __shared__ float mt[32];
    __shared__ float wqa[1024];
    int b = blockIdx.x;
    int tid = threadIdx.x;   // 512

    if (b < NBLK_SORT) {
        if (tid < 200) h[tid] = 0;
        __syncthreads();
        int gid = b * 512 + tid;
        if (gid < N_NODES) {
            int combo = xarr[gid] * 2 + molid[gid];
            int pk = combo | (batch[gid] << 8);
            nodeinfo[gid] = make_float4(pos[3 * gid], pos[3 * gid + 1], pos[3 * gid + 2],
                                        __int_as_float(pk));
            zbuf[gid] = 0.0f;
        }
        if (gid < N_EDGES) {
            int s = esrc[gid];
            int cs = xarr[s] * 2 + molid[s];
            csbuf[gid] = cs;
            atomicAdd(&h[cs], 1);
        }
        if (b == 0) {
            for (int i = tid; i < N_GRAPHS * 64; i += 512) out[i] = 0.0f;
        }
        __syncthreads();
        if (tid < 200) hist[b * 200 + tid] = h[tid];
        return;
    }

    // table-builder blocks
    for (int i = tid; i < 4800; i += 512) zt[i] = z_table[i];
    if (tid < 32) mt[tid] = mol_table[tid];
    int tb = b - NBLK_SORT;      // 0..96
    if (tb == 96) {
        for (int o = tid; o < 1024; o += 512) {
            int u = o >> 4, w = o & 15;
            float s = 0.0f;
#pragma unroll
            for (int v = 0; v < 16; ++v) s += Wq[u * 16 + v] * Wa[v * 16 + w];
            wqa[o] = s;
        }
        // per-graph inverse node counts (batch is sorted)
        if (tid < N_GRAPHS) {
            int g = tid;
            int lo = 0, hi = N_NODES;
            while (lo < hi) { int m = (lo + hi) >> 1; if (batch[m] < g) lo = m + 1; else hi = m; }
            int st = lo;
            lo = st; hi = N_NODES;
            while (lo < hi) { int m = (lo + hi) >> 1; if (batch[m] <= g) lo = m + 1; else hi = m; }
            int c = lo - st;
            invc[g] = 1.0f / (float)((c < 1) ? 1 : c);
        }
        __syncthreads();
        for (int o = tid; o < 200 * 16; o += 512) {
            int combo = o >> 4, w = o & 15;
            int elem = combo >> 1, mol = combo & 1;
            float s = 0.0f;
#pragma unroll
            for (int u = 0; u < 48; ++u) s += zt[elem * 48 + u] * wqa[u * 16 + w];
#pragma unroll
            for (int u = 0; u < 16; ++u) s += mt[mol * 16 + u] * wqa[(48 + u) * 16 + w];
            qa[combo * 16 + w] = s * 0.125f * QK_NORM;
        }
        return;
    }
    int t = tb >> 5;         // 0=k, 1=v0, 2=v1
    int m = tb & 31;
    int w = tid & 15;
    const float* src = (t == 0) ? (W2k + m * 2048)
                     : (t == 1) ? (W2v + m * 2048)
                                : (W2v + m * 2048 + 1024);
    float w2c[64];
#pragma unroll
    for (int u = 0; u < 64; ++u) w2c[u] = src[u * 16 + w];
    __syncthreads();
    float* dstT = (t == 0) ? BkT : (t == 1) ? Bv0T : Bv1T;
    for (int o = tid; o < 200 * 16; o += 512) {   // 512%16==0 keeps w == o&15
        int combo = o >> 4;
        int elem = combo >> 1, mol = combo & 1;
        const float* f = &zt[elem * 48];
        float s = 0.0f;
#pragma unroll
        for (int u = 0; u < 48; ++u) s += f[u] * w2c[u];
        const float* mm = &mt[mol * 16];
#pragma unroll
        for (int u = 0; u < 16; ++u) s += mm[u] * w2c[48 + u];
        dstT[combo * 512 + w * 32 + m] = s * SCALE_B;
    }
}

// Scatter with INLINE redundant scan (each block recomputes offsets + its own
// per-combo base from hist). Block 0 publishes meta for edge/acc kernels.
__global__ void scatter_kernel(const int* __restrict__ csbuf,
                               const int* __restrict__ esrc, const int* __restrict__ edst,
                               const int* __restrict__ hist,
                               int* __restrict__ meta, int2* __restrict__ spair) {
    __shared__ int scnt[200];
    __shared__ int sbase[200];
    __shared__ int soff[201];
    __shared__ int cnt2[200];
    int b = blockIdx.x;
    int tid = threadIdx.x;   // 512
    if (tid < 200) {
        int tot = 0, mine = 0;
        for (int b2 = 0; b2 < NBLK_SORT; ++b2) {
            int hv = hist[b2 * 200 + tid];
            if (b2 < b) mine += hv;
            tot += hv;
        }
        scnt[tid] = tot;
        sbase[tid] = mine;
        cnt2[tid] = 0;
    }
    __syncthreads();
    if (tid == 0) {
        int acc = 0;
        for (int c = 0; c < 200; ++c) { soff[c] = acc; acc += (scnt[c] + 63) & ~63; }
        soff[200] = acc;
    }
    __syncthreads();
    if (tid < 200) sbase[tid] += soff[tid];
    if (b == 0) {
        if (tid < 200) meta[tid] = scnt[tid];
        if (tid < 201) meta[400 + tid] = soff[tid];
        if (tid == 0) meta[601] = soff[200];
    }
    __syncthreads();
    int e = b * 512 + tid;
    if (e < N_EDGES) {
        int cs = csbuf[e];
        int r = atomicAdd(&cnt2[cs], 1);     // LDS atomic: block-local
        spair[sbase[cs] + r] = make_int2(esrc[e], edst[e]);
    }
}

// Bucketed edge pass: one combo per block, tables staged in LDS (stride 36).
__global__ void edge_kernel(const int2* __restrict__ spair,
                            const float4* __restrict__ nodeinfo,
                            const float* __restrict__ W1k, const float* __restrict__ W1v,
                            const float* __restrict__ BkT, const float* __restrict__ Bv0T,
                            const float* __restrict__ Bv1T, const float* __restrict__ qa,
                            const int* __restrict__ meta,
                            float4* __restrict__ geomexp, int* __restrict__ pkbuf,
                            float2* __restrict__ vsbuf, float* __restrict__ zbuf) {
    __shared__ float Bk_s[16 * 36], Bv0_s[16 * 36], Bv1_s[16 * 36];
    __shared__ float w1k_s[10 * 33], w1v_s[10 * 33];
    __shared__ float hk[16][36], hv[16][36];
    int b = blockIdx.x;
    int base = b * 64;
    int ptot = meta[601];
    if (base >= ptot) return;
    const int* poff = meta + 400;
    int lo = 0, hi = 200;
    while (lo < hi) { int m = (lo + hi) >> 1; if (poff[m + 1] <= base) lo = m + 1; else hi = m; }
    int combo = lo;
    int vend = poff[combo] + meta[combo];    // first invalid slot in this bucket
    int tid = threadIdx.x, lane = tid & 15, grp = tid >> 4;
    for (int o = tid; o < 512; o += 256) {
        int w = o >> 5, m = o & 31;
        Bk_s [w * 36 + m] = BkT [combo * 512 + o];
        Bv0_s[w * 36 + m] = Bv0T[combo * 512 + o];
        Bv1_s[w * 36 + m] = Bv1T[combo * 512 + o];
    }
    for (int o = tid; o < 330; o += 256) {
        int i = o / 33, ch = o % 33;
        if (ch < 32) {
            w1k_s[o] = W1k[i * 32 + ch];
            w1v_s[o] = W1v[i * 32 + ch];
        }
    }
    __syncthreads();
#pragma unroll
    for (int it = 0; it < 4; ++it) {
        int idx = base + it * 16 + grp;
        if (idx < vend) {
            int2 sd = spair[idx];
            float4 ns = nodeinfo[sd.x];
            float4 nd = nodeinfo[sd.y];
            float vx = ns.x - nd.x, vy = ns.y - nd.y, vz = ns.z - nd.z;
            float len = sqrtf(vx * vx + vy * vy + vz * vz);
            int pkd = __float_as_int(nd.w);
            int cd = pkd & 255;
            int g = pkd >> 8;

            float t = len * RSTEP;
            int i1 = (int)floorf(t);
            int i0 = i1 - 1;
            float d1 = t - (float)(i1 + 1);
            float d0 = d1 + 1.0f;
            float b1v = (i1 <= 9) ? bval(d1) : 0.0f;
            float b0v = (i0 >= 0) ? bval(d0) : 0.0f;
            int i1c = min(max(i1, 0), 9);
            int i0c = min(max(i0, 0), 9);

            float sk0 = b0v * w1k_s[i0c * 33 + lane]      + b1v * w1k_s[i1c * 33 + lane];
            float sk1 = b0v * w1k_s[i0c * 33 + lane + 16] + b1v * w1k_s[i1c * 33 + lane + 16];
            float sv0 = b0v * w1v_s[i0c * 33 + lane]      + b1v * w1v_s[i1c * 33 + lane];
            float sv1 = b0v * w1v_s[i0c * 33 + lane + 16] + b1v * w1v_s[i1c * 33 + lane + 16];
            hk[grp][lane]      = silu_n(sk0 * INV_SQRT10);
            hk[grp][lane + 16] = silu_n(sk1 * INV_SQRT10);
            hv[grp][lane]      = silu_n(sv0 * INV_SQRT10);
            hv[grp][lane + 16] = silu_n(sv1 * INV_SQRT10);

            const float4* hpk = (const float4*)&hk[grp][0];
            const float4* hpv = (const float4*)&hv[grp][0];
            const float4* bks = (const float4*)&Bk_s [lane * 36];
            const float4* b0s = (const float4*)&Bv0_s[lane * 36];
            const float4* b1s = (const float4*)&Bv1_s[lane * 36];
            float k0 = 0.0f, v0 = 0.0f, s1v = 0.0f;
#pragma unroll
            for (int mq = 0; mq < 8; ++mq) {
                float4 h4 = hpk[mq];
                float4 a  = bks[mq];
                k0 += h4.x * a.x + h4.y * a.y + h4.z * a.z + h4.w * a.w;
                float4 g4 = hpv[mq];
                float4 a0 = b0s[mq];
                float4 a1 = b1s[mq];
                v0  += g4.x * a0.x + g4.y * a0.y + g4.z * a0.z + g4.w * a0.w;
                s1v += g4.x * a1.x + g4.y * a1.y + g4.z * a1.z + g4.w * a1.w;
            }
            float p = qa[cd * 16 + lane] * k0;
#pragma unroll
            for (int off = 1; off < 16; off <<= 1) p += __shfl_xor(p, off, 16);

            vsbuf[idx * 16 + lane] = make_float2(v0, s1v);
            if (lane == 0) {
                float cutoff = sus_f(10.0f * (1.0f - len * (1.0f / 6.0f)));
                float ev = cutoff * __expf(p);
                atomicAdd(&zbuf[sd.y], ev);
                float il = SQRT3 / len;
                geomexp[idx] = make_float4(vx * il, vy * il, vz * il, ev);
                pkbuf[idx] = sd.y | (g << 14);
            }
        } else {
            vsbuf[idx * 16 + lane] = make_float2(0.0f, 0.0f);
            if (lane == 0) {
                geomexp[idx] = make_float4(0.0f, 0.0f, 0.0f, 0.0f);
                pkbuf[idx] = 0;
            }
        }
    }
}

// Accumulate: att = sqrt(ev/z), LDS per-graph tile, then flush directly into
// d_out via non-returning global atomics scaled by 1/count[g].
// NO device-scope fences (they cost 60-130us on this 8-XCD part).
__global__ void __launch_bounds__(1024)
acc_kernel(const float4* __restrict__ geomexp, const int* __restrict__ pkbuf,
           const float2* __restrict__ vsbuf, const float* __restrict__ zbuf,
           const int* __restrict__ meta, const float* __restrict__ invc,
           float* __restrict__ out) {
    __shared__ float acc[N_GRAPHS * 68];
    __shared__ float invc_s[N_GRAPHS];
    int tid = threadIdx.x;
    int lane = tid & 15;
    int grp = tid >> 4;
    int ptot = meta[601];
    for (int i = tid; i < N_GRAPHS * 68; i += 1024) acc[i] = 0.0f;
    if (tid < N_GRAPHS) invc_s[tid] = invc[tid];
    __syncthreads();
    int gid = blockIdx.x * 64 + grp;
    for (int e = gid; e < ptot; e += NACC * 64) {
        float4 ge = geomexp[e];
        int pk = pkbuf[e];
        float2 vs = vsbuf[e * 16 + lane];
        int dst = pk & 16383;
        int g = pk >> 14;
        float z = zbuf[dst];
        if (z == 0.0f) z = 1.0f;
        float att = sqrtf(__fdividef(ge.w, z));
        float v0 = vs.x * att;
        float s1v = vs.y * att;
        float* row = &acc[g * 68];
        atomicAdd(&row[lane], v0);
        atomicAdd(&row[16 + lane * 3 + 0], s1v * ge.x);
        atomicAdd(&row[16 + lane * 3 + 1], s1v * ge.y);
        atomicAdd(&row[16 + lane * 3 + 2], s1v * ge.z);
    }
    __syncthreads();
    for (int i = tid; i < N_GRAPHS * 64; i += 1024) {
        float v = acc[(i >> 6) * 68 + (i & 63)];
        if (v != 0.0f) atomicAdd(&out[i], v * invc_s[i >> 6]);
    }
}

extern "C" void kernel_launch(void* const* d_in, const int* in_sizes, int n_in,
                              void* d_out, int out_size, void* d_ws, size_t ws_size,
                              hipStream_t stream) {
    const float* pos       = (const float*)d_in[0];
    const float* z_table   = (const float*)d_in[1];
    const float* mol_table = (const float*)d_in[2];
    const float* Wq        = (const float*)d_in[3];
    const float* W1k       = (const float*)d_in[4];
    const float* W2k       = (const float*)d_in[5];
    const float* W1v       = (const float*)d_in[6];
    const float* W2v       = (const float*)d_in[7];
    const float* Wa        = (const float*)d_in[8];
    // d_in[9] = Wb: unused (q1 == 0 in the reference)
    const int* x     = (const int*)d_in[10];
    const int* molid = (const int*)d_in[11];
    const int* esrc  = (const int*)d_in[12];
    const int* edst  = (const int*)d_in[13];
    const int* batch = (const int*)d_in[14];
    float* out = (float*)d_out;

    float* ws = (float*)d_ws;
    float4* geomexp  = (float4*)ws;                         // 93440 f4 -> 373760 floats
    float4* nodeinfo = (float4*)(ws + 373760);              // 64000
    float*  BkT      = ws + 437760;                         // 102400
    float*  Bv0T     = ws + 540160;                         // 102400
    float*  Bv1T     = ws + 642560;                         // 102400
    float*  qa       = ws + 744960;                         // 3200
    float*  zbuf     = ws + 748160;                         // 16000
    int*    meta     = (int*)(ws + 764160);                 // 1024
    float*  invc     = ws + 765184;                         // 64 (reuses old partial slot)
    float2* vsbuf    = (float2*)(ws + 1813760);             // 93440*16 f2 = 2990080
    int2*   spair    = (int2*)(ws + 4803840);               // 93440 int2 = 186880
    int*    csbuf    = (int*)(ws + 4990720);                // 80000
    int*    hist     = (int*)(ws + 5070720);                // 157*200 = 31400
    int*    pkbuf    = (int*)(ws + 5102120);                // 93440  (~20.8 MB total)

    prep_kernel<<<NBLK_SORT + 97, 512, 0, stream>>>(pos, x, molid, batch, esrc,
                                                    z_table, mol_table, Wq, Wa, W2k, W2v,
                                                    nodeinfo, zbuf, csbuf, hist,
                                                    BkT, Bv0T, Bv1T, qa, invc, out);
    scatter_kernel<<<NBLK_SORT, 512, 0, stream>>>(csbuf, esrc, edst, hist, meta, spair);
    edge_kernel<<<NB_EDGE, 256, 0, stream>>>(spair, nodeinfo, W1k, W1v,
                                             BkT, Bv0T, Bv1T, qa, meta,
                                             geomexp, pkbuf, vsbuf, zbuf);
    acc_kernel<<<NACC, 1024, 0, stream>>>(geomexp, pkbuf, vsbuf, zbuf, meta, invc, out);
}